// Round 9
// baseline (1341.509 us; speedup 1.0000x reference)
//
#include <hip/hip_runtime.h>
#include <hip/hip_bf16.h>

// ---- problem constants (fixed by the reference) ----
#define N_BONDS 196608
#define HID     256
#define NSEG    4096
#define SMSCALE 0.17677669529663687f  // D^-0.5, D=32
#define LN_EPS  1e-5f
#define SB      8                     // bonds per thread in segment kernels (block: 32 ranges x 8 heads)

typedef __hip_bfloat16 bf16;
typedef __attribute__((ext_vector_type(8))) short short8_t;  // 8 x bf16 (4 VGPR)
typedef __attribute__((ext_vector_type(4))) float f32x4_t;

__device__ __forceinline__ short f2bs(float f) {
    union { bf16 b; short s; } cv; cv.b = __float2bfloat16(f); return cv.s;
}
__device__ __forceinline__ float us2f(ushort u) {
    union { ushort u; bf16 b; } cv; cv.u = u; return __bfloat162float(cv.b);
}

// ---------------- f32 -> bf16 cast (x4 vectorized) ----------------
__global__ void cast_kernel(const float* __restrict__ src, ushort* __restrict__ dst, int n4) {
    int i = blockIdx.x * blockDim.x + threadIdx.x;
    const int stride = gridDim.x * blockDim.x;
    for (; i < n4; i += stride) {
        float4 v = reinterpret_cast<const float4*>(src)[i];
        union { ushort4 u; bf16 b[4]; } cv;
        cv.b[0] = __float2bfloat16(v.x);
        cv.b[1] = __float2bfloat16(v.y);
        cv.b[2] = __float2bfloat16(v.z);
        cv.b[3] = __float2bfloat16(v.w);
        reinterpret_cast<ushort4*>(dst)[i] = cv.u;
    }
}

// ---------------- GEMM: C[n,j] = sum_i A[n,i] * W[j,i]  (torch Linear, B^T form) ----------------
// VERBATIM from R1/R6 (known-pass). grid.x = M/128 row tiles, grid.y = 2 col halves.
template <typename OutT>
__global__ __launch_bounds__(256, 2) void gemm_bt(const ushort* __restrict__ A,
                                                  const ushort* __restrict__ W,
                                                  OutT* __restrict__ C) {
    __shared__ __align__(16) char lds[128 * 512];
    const int t = threadIdx.x;
    const int colhalf = blockIdx.y;
#pragma unroll
    for (int it = 0; it < 16; ++it) {
        int c = it * 256 + t;
        int j = c >> 5, kc = c & 31;
        uint4 val = *reinterpret_cast<const uint4*>(W + ((colhalf << 7) + j) * HID + (kc << 3));
        *reinterpret_cast<uint4*>(lds + j * 512 + ((kc << 4) ^ ((j & 7) << 4))) = val;
    }
    __syncthreads();

    const int wave = t >> 6, lane = t & 63;
    const int lr = lane & 15, lk = lane >> 4;
    const long rowbase = (long)blockIdx.x * 128 + wave * 32;

    f32x4_t acc[2][8];
#pragma unroll
    for (int r = 0; r < 2; ++r)
#pragma unroll
        for (int cc = 0; cc < 8; ++cc) acc[r][cc] = (f32x4_t){0.f, 0.f, 0.f, 0.f};

    const ushort* a0 = A + (rowbase + lr) * HID;
    const ushort* a1 = a0 + 16 * HID;
#pragma unroll
    for (int k0 = 0; k0 < HID; k0 += 32) {
        const int koff = k0 + lk * 8;
        short8_t af0 = *reinterpret_cast<const short8_t*>(a0 + koff);
        short8_t af1 = *reinterpret_cast<const short8_t*>(a1 + koff);
#pragma unroll
        for (int cc = 0; cc < 8; ++cc) {
            const int j = cc * 16 + lr;
            short8_t bfr = *reinterpret_cast<const short8_t*>(
                lds + j * 512 + (((k0 << 1) + (lk << 4)) ^ ((j & 7) << 4)));
            acc[0][cc] = __builtin_amdgcn_mfma_f32_16x16x32_bf16(af0, bfr, acc[0][cc], 0, 0, 0);
            acc[1][cc] = __builtin_amdgcn_mfma_f32_16x16x32_bf16(af1, bfr, acc[1][cc], 0, 0, 0);
        }
    }
    // C/D layout (verified m89): col = lane&15, row = (lane>>4)*4 + reg
#pragma unroll
    for (int r = 0; r < 2; ++r) {
#pragma unroll
        for (int cc = 0; cc < 8; ++cc) {
            const int col = (colhalf << 7) + cc * 16 + lr;
#pragma unroll
            for (int reg = 0; reg < 4; ++reg) {
                const long row = rowbase + r * 16 + lk * 4 + reg;
                const float v = acc[r][cc][reg];
                if constexpr (sizeof(OutT) == 2) C[row * HID + col] = __float2bfloat16(v);
                else                             C[row * HID + col] = v;
            }
        }
    }
}

// ---------------- alpha = softmax_d(q*w_alpha*scale); gq = segment_sum(alpha*q) ----------------
// One thread per (bond-range, head); zero cross-lane ops. Segment accumulator acc[32] lives in
// LDS (pad 33 -> (t+d)%32 banks, 2 lanes/bank = free): R7/R8 showed hipcc spills loop-carried
// 32-float register arrays to scratch (WRITE_SIZE 161-195 MB, occ 14%); LDS is unspillable.
// q stays packed bf16 (16 VGPR); exp recomputed per pass. No max-subtraction: |x| <= ~3 so
// exp(x)/sum(exp(x)) is f32-safe and mathematically identical to the max-shifted reference.
__global__ __launch_bounds__(256, 2) void alpha_gq_kernel(const ushort* __restrict__ qb,
                                                          const float* __restrict__ w_alpha,
                                                          const int* __restrict__ seg,
                                                          float* __restrict__ gq) {
    __shared__ float wa_s[32];
    __shared__ float acc_s[256 * 33];
    const int t = threadIdx.x;
    if (t < 32) wa_s[t] = w_alpha[t] * SMSCALE;
    float* acc = acc_s + t * 33;
#pragma unroll
    for (int d = 0; d < 32; ++d) acc[d] = 0.f;
    __syncthreads();

    const int h = t & 7, c = t >> 3;
    const long nbase = (long)blockIdx.x * (32 * SB) + (long)c * SB;
    int cur = seg[nbase];

    for (int i = 0; i < SB; ++i) {
        const long n = nbase + i;
        const int s = seg[n];
        const ushort* qp = qb + n * HID + h * 32;
        short8_t q8[4];
#pragma unroll
        for (int v = 0; v < 4; ++v) q8[v] = *reinterpret_cast<const short8_t*>(qp + v * 8);

        float ssum = 0.f;
#pragma unroll
        for (int d = 0; d < 32; ++d)
            ssum += __expf(us2f((ushort)q8[d >> 3][d & 7]) * wa_s[d]);
        const float inv = 1.f / ssum;

        if (s != cur) {
            float* gp = gq + (long)cur * HID + h * 32;
#pragma unroll
            for (int d = 0; d < 32; ++d) { atomicAdd(gp + d, acc[d]); acc[d] = 0.f; }
            cur = s;
        }
#pragma unroll
        for (int d = 0; d < 32; ++d) {
            const float qv = us2f((ushort)q8[d >> 3][d & 7]);
            acc[d] = fmaf(__expf(qv * wa_s[d]) * inv, qv, acc[d]);
        }
    }
    float* gp = gq + (long)cur * HID + h * 32;
#pragma unroll
    for (int d = 0; d < 32; ++d) atomicAdd(gp + d, acc[d]);
}

// ---------------- p = gq[seg]*k; beta = softmax_d(p*w_beta*scale); gk = segment_sum(beta*p) ----
// Same LDS-accumulator structure. gq row slice is re-gathered from global per pass instead of
// held in registers (gq = 4 MB total -> L2/L3-resident; ~400 MB L2 traffic ~= 13 us).
__global__ __launch_bounds__(256, 2) void beta_gk_kernel(const ushort* __restrict__ kb,
                                                         const float* __restrict__ gq,
                                                         const float* __restrict__ w_beta,
                                                         const int* __restrict__ seg,
                                                         float* __restrict__ gk) {
    __shared__ float wb_s[32];
    __shared__ float acc_s[256 * 33];
    const int t = threadIdx.x;
    if (t < 32) wb_s[t] = w_beta[t] * SMSCALE;
    float* acc = acc_s + t * 33;
#pragma unroll
    for (int d = 0; d < 32; ++d) acc[d] = 0.f;
    __syncthreads();

    const int h = t & 7, c = t >> 3;
    const long nbase = (long)blockIdx.x * (32 * SB) + (long)c * SB;
    int cur = seg[nbase];

    for (int i = 0; i < SB; ++i) {
        const long n = nbase + i;
        const int s = seg[n];
        const ushort* kp = kb + n * HID + h * 32;
        short8_t k8[4];
#pragma unroll
        for (int v = 0; v < 4; ++v) k8[v] = *reinterpret_cast<const short8_t*>(kp + v * 8);
        const float* gp2 = gq + (long)s * HID + h * 32;

        float ssum = 0.f;
#pragma unroll
        for (int dq = 0; dq < 8; ++dq) {
            float4 g4 = reinterpret_cast<const float4*>(gp2)[dq];
#pragma unroll
            for (int e = 0; e < 4; ++e) {
                const int d = dq * 4 + e;
                const float ge = (e == 0) ? g4.x : (e == 1) ? g4.y : (e == 2) ? g4.z : g4.w;
                ssum += __expf(ge * us2f((ushort)k8[d >> 3][d & 7]) * wb_s[d]);
            }
        }
        const float inv = 1.f / ssum;

        if (s != cur) {
            float* gpk = gk + (long)cur * HID + h * 32;
#pragma unroll
            for (int d = 0; d < 32; ++d) { atomicAdd(gpk + d, acc[d]); acc[d] = 0.f; }
            cur = s;
        }
#pragma unroll
        for (int dq = 0; dq < 8; ++dq) {
            float4 g4 = reinterpret_cast<const float4*>(gp2)[dq];
#pragma unroll
            for (int e = 0; e < 4; ++e) {
                const int d = dq * 4 + e;
                const float ge = (e == 0) ? g4.x : (e == 1) ? g4.y : (e == 2) ? g4.z : g4.w;
                const float p = ge * us2f((ushort)k8[d >> 3][d & 7]);
                acc[d] = fmaf(__expf(p * wb_s[d]) * inv, p, acc[d]);
            }
        }
    }
    float* gpk = gk + (long)cur * HID + h * 32;
#pragma unroll
    for (int d = 0; d < 32; ++d) atomicAdd(gpk + d, acc[d]);
}

// ---------------- act = relu((gk[seg]*v) @ W_r^T per head + q), EXACT f32 ------------------
// VERBATIM from R6 (known-pass).
__global__ __launch_bounds__(256) void act_exact_kernel(const ushort* __restrict__ vb,
                                                        const ushort* __restrict__ qb,
                                                        const float* __restrict__ gk,
                                                        const float* __restrict__ Wr,
                                                        const int* __restrict__ seg,
                                                        ushort* __restrict__ act) {
    __shared__ __align__(16) float wr_lds[1024];
    const int t = threadIdx.x;
#pragma unroll
    for (int i = 0; i < 4; ++i) wr_lds[i * 256 + t] = Wr[i * 256 + t];
    __syncthreads();

    const long tid = (long)blockIdx.x * 256 + t;  // flat (n, h) row index
    const int n = (int)(tid >> 3), h = (int)(tid & 7);
    const int sid = seg[n];

    const float* gp = gk + (long)sid * HID + h * 32;
    const ushort* vp = vb + tid * 32;
    float kvi[32];
#pragma unroll
    for (int dq = 0; dq < 4; ++dq) {
        short8_t v8 = *reinterpret_cast<const short8_t*>(vp + dq * 8);
        float4 ga = reinterpret_cast<const float4*>(gp)[dq * 2];
        float4 gb = reinterpret_cast<const float4*>(gp)[dq * 2 + 1];
        kvi[dq * 8 + 0] = ga.x * us2f((ushort)v8[0]);
        kvi[dq * 8 + 1] = ga.y * us2f((ushort)v8[1]);
        kvi[dq * 8 + 2] = ga.z * us2f((ushort)v8[2]);
        kvi[dq * 8 + 3] = ga.w * us2f((ushort)v8[3]);
        kvi[dq * 8 + 4] = gb.x * us2f((ushort)v8[4]);
        kvi[dq * 8 + 5] = gb.y * us2f((ushort)v8[5]);
        kvi[dq * 8 + 6] = gb.z * us2f((ushort)v8[6]);
        kvi[dq * 8 + 7] = gb.w * us2f((ushort)v8[7]);
    }

    const ushort* qp = qb + tid * 32;
    short8_t q8[4];
#pragma unroll
    for (int i = 0; i < 4; ++i) q8[i] = *reinterpret_cast<const short8_t*>(qp + i * 8);

    short8_t ob[4];
#pragma unroll
    for (int e = 0; e < 32; ++e) {
        float acc = 0.f;
        const float4* wre = reinterpret_cast<const float4*>(wr_lds + e * 32);
#pragma unroll
        for (int dq = 0; dq < 8; ++dq) {
            float4 w = wre[dq];
            acc = fmaf(kvi[dq * 4 + 0], w.x, acc);
            acc = fmaf(kvi[dq * 4 + 1], w.y, acc);
            acc = fmaf(kvi[dq * 4 + 2], w.z, acc);
            acc = fmaf(kvi[dq * 4 + 3], w.w, acc);
        }
        const float qv = us2f((ushort)q8[e >> 3][e & 7]);
        ob[e >> 3][e & 7] = f2bs(fmaxf(acc + qv, 0.f));
    }

    ushort* ap = act + tid * 32;
#pragma unroll
    for (int i = 0; i < 4; ++i) *reinterpret_cast<short8_t*>(ap + i * 8) = ob[i];
}

// ---------------- LayerNorm: one wave per row (4 f32 per lane), write d_out row n+1 ----------
// VERBATIM from R1/R6 (known-pass).
__global__ __launch_bounds__(256) void ln_kernel(const float* __restrict__ tmp,
                                                 const float* __restrict__ b_o,
                                                 const float* __restrict__ gamma,
                                                 const float* __restrict__ beta_ln,
                                                 float* __restrict__ out) {
    const int wave = threadIdx.x >> 6, lane = threadIdx.x & 63;
    const long row = (long)blockIdx.x * 4 + wave;
    const float4 bo = reinterpret_cast<const float4*>(b_o)[lane];
    const float4 g = reinterpret_cast<const float4*>(gamma)[lane];
    const float4 bl = reinterpret_cast<const float4*>(beta_ln)[lane];
    float4 x = reinterpret_cast<const float4*>(tmp + row * HID)[lane];
    x.x += bo.x; x.y += bo.y; x.z += bo.z; x.w += bo.w;
    float s = x.x + x.y + x.z + x.w;
#pragma unroll
    for (int m = 32; m >= 1; m >>= 1) s += __shfl_xor(s, m);
    const float mu = s * (1.f / HID);
    float4 dx = {x.x - mu, x.y - mu, x.z - mu, x.w - mu};
    float sq = dx.x * dx.x + dx.y * dx.y + dx.z * dx.z + dx.w * dx.w;
#pragma unroll
    for (int m = 32; m >= 1; m >>= 1) sq += __shfl_xor(sq, m);
    const float r = rsqrtf(sq * (1.f / HID) + LN_EPS);
    float4 o;
    o.x = dx.x * r * g.x + bl.x;
    o.y = dx.y * r * g.y + bl.y;
    o.z = dx.z * r * g.z + bl.z;
    o.w = dx.w * r * g.w + bl.w;
    reinterpret_cast<float4*>(out + (row + 1) * HID)[lane] = o;
}

extern "C" void kernel_launch(void* const* d_in, const int* in_sizes, int n_in,
                              void* d_out, int out_size, void* d_ws, size_t ws_size,
                              hipStream_t stream) {
    const float* msg    = (const float*)d_in[0];
    const float* Wq     = (const float*)d_in[1];
    const float* Wk     = (const float*)d_in[2];
    const float* Wv     = (const float*)d_in[3];
    const float* Wr     = (const float*)d_in[4];
    const float* walpha = (const float*)d_in[5];
    const float* wbeta  = (const float*)d_in[6];
    const float* Wo     = (const float*)d_in[7];
    const float* bo     = (const float*)d_in[8];
    const float* gamma  = (const float*)d_in[9];
    const float* betaln = (const float*)d_in[10];
    const int*   seg    = (const int*)d_in[11];

    // workspace layout (R1-identical): msgb | qb | kb | vb | wqb wkb wvb wob | gq gk
    // act (bf16) reuses msgb; tmp (f32, N*H) reuses qb+kb (dead after act).
    char* ws = (char*)d_ws;
    const size_t nh = (size_t)N_BONDS * HID;
    size_t off = 0;
    bf16* msgb = (bf16*)(ws + off); off += nh * 2;
    bf16* qb   = (bf16*)(ws + off); off += nh * 2;
    bf16* kb   = (bf16*)(ws + off); off += nh * 2;
    bf16* vb   = (bf16*)(ws + off); off += nh * 2;
    bf16* wqb  = (bf16*)(ws + off); off += (size_t)HID * HID * 2;
    bf16* wkb  = (bf16*)(ws + off); off += (size_t)HID * HID * 2;
    bf16* wvb  = (bf16*)(ws + off); off += (size_t)HID * HID * 2;
    bf16* wob  = (bf16*)(ws + off); off += (size_t)HID * HID * 2;
    float* gq  = (float*)(ws + off); off += (size_t)NSEG * HID * 4;
    float* gk  = (float*)(ws + off); off += (size_t)NSEG * HID * 4;
    bf16*  act = msgb;
    float* tmp = (float*)qb;

    hipMemsetAsync(gq, 0, (size_t)2 * NSEG * HID * 4, stream);
    hipMemsetAsync(d_out, 0, HID * sizeof(float), stream);

    cast_kernel<<<4096, 256, 0, stream>>>(msg, (ushort*)msgb, (int)(nh / 4));
    cast_kernel<<<64, 256, 0, stream>>>(Wq, (ushort*)wqb, HID * HID / 4);
    cast_kernel<<<64, 256, 0, stream>>>(Wk, (ushort*)wkb, HID * HID / 4);
    cast_kernel<<<64, 256, 0, stream>>>(Wv, (ushort*)wvb, HID * HID / 4);
    cast_kernel<<<64, 256, 0, stream>>>(Wo, (ushort*)wob, HID * HID / 4);

    dim3 gg(N_BONDS / 128, 2);
    gemm_bt<bf16><<<gg, 256, 0, stream>>>((const ushort*)msgb, (const ushort*)wqb, qb);
    gemm_bt<bf16><<<gg, 256, 0, stream>>>((const ushort*)msgb, (const ushort*)wkb, kb);
    gemm_bt<bf16><<<gg, 256, 0, stream>>>((const ushort*)msgb, (const ushort*)wvb, vb);

    alpha_gq_kernel<<<N_BONDS / (32 * SB), 256, 0, stream>>>((const ushort*)qb, walpha, seg, gq);
    beta_gk_kernel<<<N_BONDS / (32 * SB), 256, 0, stream>>>((const ushort*)kb, gq, wbeta, seg, gk);

    act_exact_kernel<<<N_BONDS * 8 / 256, 256, 0, stream>>>((const ushort*)vb, (const ushort*)qb,
                                                            gk, Wr, seg, (ushort*)act);

    gemm_bt<float><<<gg, 256, 0, stream>>>((const ushort*)act, (const ushort*)wob, tmp);
    ln_kernel<<<N_BONDS / 4, 256, 0, stream>>>(tmp, bo, gamma, betaln, (float*)d_out);
}

// Round 10
// 626.803 us; speedup vs baseline: 2.1402x; 2.1402x over previous
//
#include <hip/hip_runtime.h>
#include <hip/hip_bf16.h>

// ---- problem constants (fixed by the reference) ----
#define N_BONDS 196608
#define HID     256
#define NSEG    4096
#define SMSCALE 0.17677669529663687f  // D^-0.5, D=32
#define LN_EPS  1e-5f
#define CHUNK   8                     // bonds per block in segment kernels (R6 had 64: serial-chain-bound)

typedef __hip_bfloat16 bf16;
typedef __attribute__((ext_vector_type(8))) short short8_t;  // 8 x bf16 (4 VGPR)
typedef __attribute__((ext_vector_type(4))) float f32x4_t;

__device__ __forceinline__ float bf2f(bf16 x) { return __bfloat162float(x); }
__device__ __forceinline__ short f2bs(float f) {
    union { bf16 b; short s; } cv; cv.b = __float2bfloat16(f); return cv.s;
}
__device__ __forceinline__ float us2f(ushort u) {
    union { ushort u; bf16 b; } cv; cv.u = u; return __bfloat162float(cv.b);
}

// 32-lane-group sum inside a 64-lane wave (xor masks < 32 stay inside the head group)
__device__ __forceinline__ float gsum32(float x) {
#pragma unroll
    for (int m = 16; m >= 1; m >>= 1) x += __shfl_xor(x, m);
    return x;
}

// ---------------- f32 -> bf16 cast (x4 vectorized) ----------------
__global__ void cast_kernel(const float* __restrict__ src, ushort* __restrict__ dst, int n4) {
    int i = blockIdx.x * blockDim.x + threadIdx.x;
    const int stride = gridDim.x * blockDim.x;
    for (; i < n4; i += stride) {
        float4 v = reinterpret_cast<const float4*>(src)[i];
        union { ushort4 u; bf16 b[4]; } cv;
        cv.b[0] = __float2bfloat16(v.x);
        cv.b[1] = __float2bfloat16(v.y);
        cv.b[2] = __float2bfloat16(v.z);
        cv.b[3] = __float2bfloat16(v.w);
        reinterpret_cast<ushort4*>(dst)[i] = cv.u;
    }
}

// ---------------- GEMM: C[n,j] = sum_i A[n,i] * W[j,i]  (torch Linear, B^T form) ----------------
// VERBATIM from R1/R6 (known-pass). grid.x = M/128 row tiles, grid.y = 2 col halves.
template <typename OutT>
__global__ __launch_bounds__(256, 2) void gemm_bt(const ushort* __restrict__ A,
                                                  const ushort* __restrict__ W,
                                                  OutT* __restrict__ C) {
    __shared__ __align__(16) char lds[128 * 512];
    const int t = threadIdx.x;
    const int colhalf = blockIdx.y;
#pragma unroll
    for (int it = 0; it < 16; ++it) {
        int c = it * 256 + t;
        int j = c >> 5, kc = c & 31;
        uint4 val = *reinterpret_cast<const uint4*>(W + ((colhalf << 7) + j) * HID + (kc << 3));
        *reinterpret_cast<uint4*>(lds + j * 512 + ((kc << 4) ^ ((j & 7) << 4))) = val;
    }
    __syncthreads();

    const int wave = t >> 6, lane = t & 63;
    const int lr = lane & 15, lk = lane >> 4;
    const long rowbase = (long)blockIdx.x * 128 + wave * 32;

    f32x4_t acc[2][8];
#pragma unroll
    for (int r = 0; r < 2; ++r)
#pragma unroll
        for (int cc = 0; cc < 8; ++cc) acc[r][cc] = (f32x4_t){0.f, 0.f, 0.f, 0.f};

    const ushort* a0 = A + (rowbase + lr) * HID;
    const ushort* a1 = a0 + 16 * HID;
#pragma unroll
    for (int k0 = 0; k0 < HID; k0 += 32) {
        const int koff = k0 + lk * 8;
        short8_t af0 = *reinterpret_cast<const short8_t*>(a0 + koff);
        short8_t af1 = *reinterpret_cast<const short8_t*>(a1 + koff);
#pragma unroll
        for (int cc = 0; cc < 8; ++cc) {
            const int j = cc * 16 + lr;
            short8_t bfr = *reinterpret_cast<const short8_t*>(
                lds + j * 512 + (((k0 << 1) + (lk << 4)) ^ ((j & 7) << 4)));
            acc[0][cc] = __builtin_amdgcn_mfma_f32_16x16x32_bf16(af0, bfr, acc[0][cc], 0, 0, 0);
            acc[1][cc] = __builtin_amdgcn_mfma_f32_16x16x32_bf16(af1, bfr, acc[1][cc], 0, 0, 0);
        }
    }
    // C/D layout (verified m89): col = lane&15, row = (lane>>4)*4 + reg
#pragma unroll
    for (int r = 0; r < 2; ++r) {
#pragma unroll
        for (int cc = 0; cc < 8; ++cc) {
            const int col = (colhalf << 7) + cc * 16 + lr;
#pragma unroll
            for (int reg = 0; reg < 4; ++reg) {
                const long row = rowbase + r * 16 + lk * 4 + reg;
                const float v = acc[r][cc][reg];
                if constexpr (sizeof(OutT) == 2) C[row * HID + col] = __float2bfloat16(v);
                else                             C[row * HID + col] = v;
            }
        }
    }
}

// ---------------- alpha = softmax_d(q*w_alpha*scale); gq = segment_sum(alpha*q) ----------------
// R6-green structure (one thread per (h,d) element; ONE atomic per thread per flush), with two
// deltas: CHUNK 64->8 (serial chain cut 8x -- R6's 127us was chain-latency-bound) and no-max
// softmax (5 shfls/bond not 10; |x|<=~3 so f32 exp is safe; validated green in R9's pass).
__global__ __launch_bounds__(256) void alpha_gq_kernel(const bf16* __restrict__ qb,
                                                       const float* __restrict__ w_alpha,
                                                       const int* __restrict__ seg,
                                                       float* __restrict__ gq) {
    const int j = threadIdx.x;
    const float wa = w_alpha[j & 31] * SMSCALE;
    const long n0 = (long)blockIdx.x * CHUNK;
    float acc = 0.f;
    int cur = -1;
    for (int i = 0; i < CHUNK; ++i) {
        const long n = n0 + i;
        const int s = seg[n];
        const float qv = bf2f(qb[n * HID + j]);
        const float e = __expf(qv * wa);
        const float ssum = gsum32(e);
        const float alpha = e / ssum;
        if (s != cur) {
            if (cur >= 0) atomicAdd(&gq[(long)cur * HID + j], acc);
            acc = 0.f;
            cur = s;
        }
        acc += alpha * qv;
    }
    atomicAdd(&gq[(long)cur * HID + j], acc);
}

// ---------------- p = gq[seg]*k; beta = softmax_d(p*w_beta*scale); gk = segment_sum(beta*p) ----
__global__ __launch_bounds__(256) void beta_gk_kernel(const bf16* __restrict__ kb,
                                                      const float* __restrict__ gq,
                                                      const float* __restrict__ w_beta,
                                                      const int* __restrict__ seg,
                                                      float* __restrict__ gk) {
    const int j = threadIdx.x;
    const float wb = w_beta[j & 31] * SMSCALE;
    const long n0 = (long)blockIdx.x * CHUNK;
    float acc = 0.f;
    int cur = -1;
    for (int i = 0; i < CHUNK; ++i) {
        const long n = n0 + i;
        const int s = seg[n];
        const float kv = bf2f(kb[n * HID + j]);
        const float p = gq[(long)s * HID + j] * kv;
        const float e = __expf(p * wb);
        const float ssum = gsum32(e);
        const float beta = e / ssum;
        if (s != cur) {
            if (cur >= 0) atomicAdd(&gk[(long)cur * HID + j], acc);
            acc = 0.f;
            cur = s;
        }
        acc += beta * p;
    }
    atomicAdd(&gk[(long)cur * HID + j], acc);
}

// ---------------- act = relu((gk[seg]*v) @ W_r^T per head + q), EXACT f32 ------------------
// VERBATIM from R6 (known-pass).
__global__ __launch_bounds__(256) void act_exact_kernel(const ushort* __restrict__ vb,
                                                        const ushort* __restrict__ qb,
                                                        const float* __restrict__ gk,
                                                        const float* __restrict__ Wr,
                                                        const int* __restrict__ seg,
                                                        ushort* __restrict__ act) {
    __shared__ __align__(16) float wr_lds[1024];
    const int t = threadIdx.x;
#pragma unroll
    for (int i = 0; i < 4; ++i) wr_lds[i * 256 + t] = Wr[i * 256 + t];
    __syncthreads();

    const long tid = (long)blockIdx.x * 256 + t;  // flat (n, h) row index
    const int n = (int)(tid >> 3), h = (int)(tid & 7);
    const int sid = seg[n];

    const float* gp = gk + (long)sid * HID + h * 32;
    const ushort* vp = vb + tid * 32;
    float kvi[32];
#pragma unroll
    for (int dq = 0; dq < 4; ++dq) {
        short8_t v8 = *reinterpret_cast<const short8_t*>(vp + dq * 8);
        float4 ga = reinterpret_cast<const float4*>(gp)[dq * 2];
        float4 gb = reinterpret_cast<const float4*>(gp)[dq * 2 + 1];
        kvi[dq * 8 + 0] = ga.x * us2f((ushort)v8[0]);
        kvi[dq * 8 + 1] = ga.y * us2f((ushort)v8[1]);
        kvi[dq * 8 + 2] = ga.z * us2f((ushort)v8[2]);
        kvi[dq * 8 + 3] = ga.w * us2f((ushort)v8[3]);
        kvi[dq * 8 + 4] = gb.x * us2f((ushort)v8[4]);
        kvi[dq * 8 + 5] = gb.y * us2f((ushort)v8[5]);
        kvi[dq * 8 + 6] = gb.z * us2f((ushort)v8[6]);
        kvi[dq * 8 + 7] = gb.w * us2f((ushort)v8[7]);
    }

    const ushort* qp = qb + tid * 32;
    short8_t q8[4];
#pragma unroll
    for (int i = 0; i < 4; ++i) q8[i] = *reinterpret_cast<const short8_t*>(qp + i * 8);

    short8_t ob[4];
#pragma unroll
    for (int e = 0; e < 32; ++e) {
        float acc = 0.f;
        const float4* wre = reinterpret_cast<const float4*>(wr_lds + e * 32);
#pragma unroll
        for (int dq = 0; dq < 8; ++dq) {
            float4 w = wre[dq];
            acc = fmaf(kvi[dq * 4 + 0], w.x, acc);
            acc = fmaf(kvi[dq * 4 + 1], w.y, acc);
            acc = fmaf(kvi[dq * 4 + 2], w.z, acc);
            acc = fmaf(kvi[dq * 4 + 3], w.w, acc);
        }
        const float qv = us2f((ushort)q8[e >> 3][e & 7]);
        ob[e >> 3][e & 7] = f2bs(fmaxf(acc + qv, 0.f));
    }

    ushort* ap = act + tid * 32;
#pragma unroll
    for (int i = 0; i < 4; ++i) *reinterpret_cast<short8_t*>(ap + i * 8) = ob[i];
}

// ---------------- LayerNorm: one wave per row (4 f32 per lane), write d_out row n+1 ----------
// VERBATIM from R1/R6 (known-pass).
__global__ __launch_bounds__(256) void ln_kernel(const float* __restrict__ tmp,
                                                 const float* __restrict__ b_o,
                                                 const float* __restrict__ gamma,
                                                 const float* __restrict__ beta_ln,
                                                 float* __restrict__ out) {
    const int wave = threadIdx.x >> 6, lane = threadIdx.x & 63;
    const long row = (long)blockIdx.x * 4 + wave;
    const float4 bo = reinterpret_cast<const float4*>(b_o)[lane];
    const float4 g = reinterpret_cast<const float4*>(gamma)[lane];
    const float4 bl = reinterpret_cast<const float4*>(beta_ln)[lane];
    float4 x = reinterpret_cast<const float4*>(tmp + row * HID)[lane];
    x.x += bo.x; x.y += bo.y; x.z += bo.z; x.w += bo.w;
    float s = x.x + x.y + x.z + x.w;
#pragma unroll
    for (int m = 32; m >= 1; m >>= 1) s += __shfl_xor(s, m);
    const float mu = s * (1.f / HID);
    float4 dx = {x.x - mu, x.y - mu, x.z - mu, x.w - mu};
    float sq = dx.x * dx.x + dx.y * dx.y + dx.z * dx.z + dx.w * dx.w;
#pragma unroll
    for (int m = 32; m >= 1; m >>= 1) sq += __shfl_xor(sq, m);
    const float r = rsqrtf(sq * (1.f / HID) + LN_EPS);
    float4 o;
    o.x = dx.x * r * g.x + bl.x;
    o.y = dx.y * r * g.y + bl.y;
    o.z = dx.z * r * g.z + bl.z;
    o.w = dx.w * r * g.w + bl.w;
    reinterpret_cast<float4*>(out + (row + 1) * HID)[lane] = o;
}

extern "C" void kernel_launch(void* const* d_in, const int* in_sizes, int n_in,
                              void* d_out, int out_size, void* d_ws, size_t ws_size,
                              hipStream_t stream) {
    const float* msg    = (const float*)d_in[0];
    const float* Wq     = (const float*)d_in[1];
    const float* Wk     = (const float*)d_in[2];
    const float* Wv     = (const float*)d_in[3];
    const float* Wr     = (const float*)d_in[4];
    const float* walpha = (const float*)d_in[5];
    const float* wbeta  = (const float*)d_in[6];
    const float* Wo     = (const float*)d_in[7];
    const float* bo     = (const float*)d_in[8];
    const float* gamma  = (const float*)d_in[9];
    const float* betaln = (const float*)d_in[10];
    const int*   seg    = (const int*)d_in[11];

    // workspace layout (R1-identical): msgb | qb | kb | vb | wqb wkb wvb wob | gq gk
    // act (bf16) reuses msgb; tmp (f32, N*H) reuses qb+kb (dead after act).
    char* ws = (char*)d_ws;
    const size_t nh = (size_t)N_BONDS * HID;
    size_t off = 0;
    bf16* msgb = (bf16*)(ws + off); off += nh * 2;
    bf16* qb   = (bf16*)(ws + off); off += nh * 2;
    bf16* kb   = (bf16*)(ws + off); off += nh * 2;
    bf16* vb   = (bf16*)(ws + off); off += nh * 2;
    bf16* wqb  = (bf16*)(ws + off); off += (size_t)HID * HID * 2;
    bf16* wkb  = (bf16*)(ws + off); off += (size_t)HID * HID * 2;
    bf16* wvb  = (bf16*)(ws + off); off += (size_t)HID * HID * 2;
    bf16* wob  = (bf16*)(ws + off); off += (size_t)HID * HID * 2;
    float* gq  = (float*)(ws + off); off += (size_t)NSEG * HID * 4;
    float* gk  = (float*)(ws + off); off += (size_t)NSEG * HID * 4;
    bf16*  act = msgb;
    float* tmp = (float*)qb;

    hipMemsetAsync(gq, 0, (size_t)2 * NSEG * HID * 4, stream);
    hipMemsetAsync(d_out, 0, HID * sizeof(float), stream);

    cast_kernel<<<4096, 256, 0, stream>>>(msg, (ushort*)msgb, (int)(nh / 4));
    cast_kernel<<<64, 256, 0, stream>>>(Wq, (ushort*)wqb, HID * HID / 4);
    cast_kernel<<<64, 256, 0, stream>>>(Wk, (ushort*)wkb, HID * HID / 4);
    cast_kernel<<<64, 256, 0, stream>>>(Wv, (ushort*)wvb, HID * HID / 4);
    cast_kernel<<<64, 256, 0, stream>>>(Wo, (ushort*)wob, HID * HID / 4);

    dim3 gg(N_BONDS / 128, 2);
    gemm_bt<bf16><<<gg, 256, 0, stream>>>((const ushort*)msgb, (const ushort*)wqb, qb);
    gemm_bt<bf16><<<gg, 256, 0, stream>>>((const ushort*)msgb, (const ushort*)wkb, kb);
    gemm_bt<bf16><<<gg, 256, 0, stream>>>((const ushort*)msgb, (const ushort*)wvb, vb);

    alpha_gq_kernel<<<N_BONDS / CHUNK, 256, 0, stream>>>(qb, walpha, seg, gq);
    beta_gk_kernel<<<N_BONDS / CHUNK, 256, 0, stream>>>(kb, gq, wbeta, seg, gk);

    act_exact_kernel<<<N_BONDS * 8 / 256, 256, 0, stream>>>((const ushort*)vb, (const ushort*)qb,
                                                            gk, Wr, seg, (ushort*)act);

    gemm_bt<float><<<gg, 256, 0, stream>>>((const ushort*)act, (const ushort*)wob, tmp);
    ln_kernel<<<N_BONDS / 4, 256, 0, stream>>>(tmp, bo, gamma, betaln, (float*)d_out);
}

// Round 11
// 618.906 us; speedup vs baseline: 2.1675x; 1.0128x over previous
//
#include <hip/hip_runtime.h>
#include <hip/hip_bf16.h>

// ---- problem constants (fixed by the reference) ----
#define N_BONDS 196608
#define HID     256
#define NSEG    4096
#define SMSCALE 0.17677669529663687f  // D^-0.5, D=32
#define LN_EPS  1e-5f
#define CHUNK   8                     // bonds per block in segment kernels

typedef __hip_bfloat16 bf16;
typedef __attribute__((ext_vector_type(8))) short short8_t;  // 8 x bf16 (4 VGPR)
typedef __attribute__((ext_vector_type(4))) float f32x4_t;

__device__ __forceinline__ float bf2f(bf16 x) { return __bfloat162float(x); }
__device__ __forceinline__ short f2bs(float f) {
    union { bf16 b; short s; } cv; cv.b = __float2bfloat16(f); return cv.s;
}
__device__ __forceinline__ float us2f(ushort u) {
    union { ushort u; bf16 b; } cv; cv.u = u; return __bfloat162float(cv.b);
}

// 32-lane-group sum inside a 64-lane wave (xor masks < 32 stay inside the head group)
__device__ __forceinline__ float gsum32(float x) {
#pragma unroll
    for (int m = 16; m >= 1; m >>= 1) x += __shfl_xor(x, m);
    return x;
}

// ---------------- f32 -> bf16 cast (x4 vectorized) ----------------
__global__ void cast_kernel(const float* __restrict__ src, ushort* __restrict__ dst, int n4) {
    int i = blockIdx.x * blockDim.x + threadIdx.x;
    const int stride = gridDim.x * blockDim.x;
    for (; i < n4; i += stride) {
        float4 v = reinterpret_cast<const float4*>(src)[i];
        union { ushort4 u; bf16 b[4]; } cv;
        cv.b[0] = __float2bfloat16(v.x);
        cv.b[1] = __float2bfloat16(v.y);
        cv.b[2] = __float2bfloat16(v.z);
        cv.b[3] = __float2bfloat16(v.w);
        reinterpret_cast<ushort4*>(dst)[i] = cv.u;
    }
}

// ---------------- GEMM: C[n,j] = sum_i A[n,i] * W[j,i]  (torch Linear, B^T form) ----------------
// VERBATIM from R1/R6 (known-pass). grid.x = M/128 row tiles, grid.y = 2 col halves.
template <typename OutT>
__global__ __launch_bounds__(256, 2) void gemm_bt(const ushort* __restrict__ A,
                                                  const ushort* __restrict__ W,
                                                  OutT* __restrict__ C) {
    __shared__ __align__(16) char lds[128 * 512];
    const int t = threadIdx.x;
    const int colhalf = blockIdx.y;
#pragma unroll
    for (int it = 0; it < 16; ++it) {
        int c = it * 256 + t;
        int j = c >> 5, kc = c & 31;
        uint4 val = *reinterpret_cast<const uint4*>(W + ((colhalf << 7) + j) * HID + (kc << 3));
        *reinterpret_cast<uint4*>(lds + j * 512 + ((kc << 4) ^ ((j & 7) << 4))) = val;
    }
    __syncthreads();

    const int wave = t >> 6, lane = t & 63;
    const int lr = lane & 15, lk = lane >> 4;
    const long rowbase = (long)blockIdx.x * 128 + wave * 32;

    f32x4_t acc[2][8];
#pragma unroll
    for (int r = 0; r < 2; ++r)
#pragma unroll
        for (int cc = 0; cc < 8; ++cc) acc[r][cc] = (f32x4_t){0.f, 0.f, 0.f, 0.f};

    const ushort* a0 = A + (rowbase + lr) * HID;
    const ushort* a1 = a0 + 16 * HID;
#pragma unroll
    for (int k0 = 0; k0 < HID; k0 += 32) {
        const int koff = k0 + lk * 8;
        short8_t af0 = *reinterpret_cast<const short8_t*>(a0 + koff);
        short8_t af1 = *reinterpret_cast<const short8_t*>(a1 + koff);
#pragma unroll
        for (int cc = 0; cc < 8; ++cc) {
            const int j = cc * 16 + lr;
            short8_t bfr = *reinterpret_cast<const short8_t*>(
                lds + j * 512 + (((k0 << 1) + (lk << 4)) ^ ((j & 7) << 4)));
            acc[0][cc] = __builtin_amdgcn_mfma_f32_16x16x32_bf16(af0, bfr, acc[0][cc], 0, 0, 0);
            acc[1][cc] = __builtin_amdgcn_mfma_f32_16x16x32_bf16(af1, bfr, acc[1][cc], 0, 0, 0);
        }
    }
    // C/D layout (verified m89): col = lane&15, row = (lane>>4)*4 + reg
#pragma unroll
    for (int r = 0; r < 2; ++r) {
#pragma unroll
        for (int cc = 0; cc < 8; ++cc) {
            const int col = (colhalf << 7) + cc * 16 + lr;
#pragma unroll
            for (int reg = 0; reg < 4; ++reg) {
                const long row = rowbase + r * 16 + lk * 4 + reg;
                const float v = acc[r][cc][reg];
                if constexpr (sizeof(OutT) == 2) C[row * HID + col] = __float2bfloat16(v);
                else                             C[row * HID + col] = v;
            }
        }
    }
}

// ---------------- alpha = softmax_d(q*w_alpha*scale); gq = segment_sum(alpha*q) ----------------
// VERBATIM from R10 (known-pass, ~30us).
__global__ __launch_bounds__(256) void alpha_gq_kernel(const bf16* __restrict__ qb,
                                                       const float* __restrict__ w_alpha,
                                                       const int* __restrict__ seg,
                                                       float* __restrict__ gq) {
    const int j = threadIdx.x;
    const float wa = w_alpha[j & 31] * SMSCALE;
    const long n0 = (long)blockIdx.x * CHUNK;
    float acc = 0.f;
    int cur = -1;
    for (int i = 0; i < CHUNK; ++i) {
        const long n = n0 + i;
        const int s = seg[n];
        const float qv = bf2f(qb[n * HID + j]);
        const float e = __expf(qv * wa);
        const float ssum = gsum32(e);
        const float alpha = e / ssum;
        if (s != cur) {
            if (cur >= 0) atomicAdd(&gq[(long)cur * HID + j], acc);
            acc = 0.f;
            cur = s;
        }
        acc += alpha * qv;
    }
    atomicAdd(&gq[(long)cur * HID + j], acc);
}

// ---------------- p = gq[seg]*k; beta = softmax_d(p*w_beta*scale); gk = segment_sum(beta*p) ----
// VERBATIM from R10 (known-pass).
__global__ __launch_bounds__(256) void beta_gk_kernel(const bf16* __restrict__ kb,
                                                      const float* __restrict__ gq,
                                                      const float* __restrict__ w_beta,
                                                      const int* __restrict__ seg,
                                                      float* __restrict__ gk) {
    const int j = threadIdx.x;
    const float wb = w_beta[j & 31] * SMSCALE;
    const long n0 = (long)blockIdx.x * CHUNK;
    float acc = 0.f;
    int cur = -1;
    for (int i = 0; i < CHUNK; ++i) {
        const long n = n0 + i;
        const int s = seg[n];
        const float kv = bf2f(kb[n * HID + j]);
        const float p = gq[(long)s * HID + j] * kv;
        const float e = __expf(p * wb);
        const float ssum = gsum32(e);
        const float beta = e / ssum;
        if (s != cur) {
            if (cur >= 0) atomicAdd(&gk[(long)cur * HID + j], acc);
            acc = 0.f;
            cur = s;
        }
        acc += beta * p;
    }
    atomicAdd(&gk[(long)cur * HID + j], acc);
}

// ---------------- act = relu((gk[seg]*v) @ W_r^T per head + q), EXACT f32, 2 rows/thread ----
// R10's 1-row version: 117us at 23% HBM / 41% VALU / 61% occ -> dependency-stall-bound (each
// output dot = 32-deep serial fma chain; 256 broadcast ds_read_b128 per wave). 2 rows/thread:
// LDS wave-insts halved AND two independent fma chains per e (2x ILP). Rows 2t,2t+1 share n
// (2t even) -> one seg[] read, adjacent gk rows. q/ob live set kept to 8 VGPR per row via
// per-8-column grouping (R7/R8 spill lesson: keep live arrays small and packed).
__global__ __launch_bounds__(256) void act_exact_kernel(const ushort* __restrict__ vb,
                                                        const ushort* __restrict__ qb,
                                                        const float* __restrict__ gk,
                                                        const float* __restrict__ Wr,
                                                        const int* __restrict__ seg,
                                                        ushort* __restrict__ act) {
    __shared__ __align__(16) float wr_lds[1024];
    const int t = threadIdx.x;
#pragma unroll
    for (int i = 0; i < 4; ++i) wr_lds[i * 256 + t] = Wr[i * 256 + t];
    __syncthreads();

    const long r0 = ((long)blockIdx.x * 256 + t) * 2;  // even flat (n,h) row; pair = {r0, r0+1}
    const int n = (int)(r0 >> 3);
    const int h0 = (int)(r0 & 7);                      // even; h1 = h0+1 < 8
    const int sid = seg[n];

    const float* gp0 = gk + (long)sid * HID + h0 * 32;
    const ushort* vp0 = vb + r0 * 32;
    float kvi0[32], kvi1[32];
#pragma unroll
    for (int dq = 0; dq < 4; ++dq) {
        short8_t v8 = *reinterpret_cast<const short8_t*>(vp0 + dq * 8);
        float4 ga = reinterpret_cast<const float4*>(gp0)[dq * 2];
        float4 gb = reinterpret_cast<const float4*>(gp0)[dq * 2 + 1];
        kvi0[dq * 8 + 0] = ga.x * us2f((ushort)v8[0]);
        kvi0[dq * 8 + 1] = ga.y * us2f((ushort)v8[1]);
        kvi0[dq * 8 + 2] = ga.z * us2f((ushort)v8[2]);
        kvi0[dq * 8 + 3] = ga.w * us2f((ushort)v8[3]);
        kvi0[dq * 8 + 4] = gb.x * us2f((ushort)v8[4]);
        kvi0[dq * 8 + 5] = gb.y * us2f((ushort)v8[5]);
        kvi0[dq * 8 + 6] = gb.z * us2f((ushort)v8[6]);
        kvi0[dq * 8 + 7] = gb.w * us2f((ushort)v8[7]);
    }
#pragma unroll
    for (int dq = 0; dq < 4; ++dq) {
        short8_t v8 = *reinterpret_cast<const short8_t*>(vp0 + 32 + dq * 8);
        float4 ga = reinterpret_cast<const float4*>(gp0 + 32)[dq * 2];
        float4 gb = reinterpret_cast<const float4*>(gp0 + 32)[dq * 2 + 1];
        kvi1[dq * 8 + 0] = ga.x * us2f((ushort)v8[0]);
        kvi1[dq * 8 + 1] = ga.y * us2f((ushort)v8[1]);
        kvi1[dq * 8 + 2] = ga.z * us2f((ushort)v8[2]);
        kvi1[dq * 8 + 3] = ga.w * us2f((ushort)v8[3]);
        kvi1[dq * 8 + 4] = gb.x * us2f((ushort)v8[4]);
        kvi1[dq * 8 + 5] = gb.y * us2f((ushort)v8[5]);
        kvi1[dq * 8 + 6] = gb.z * us2f((ushort)v8[6]);
        kvi1[dq * 8 + 7] = gb.w * us2f((ushort)v8[7]);
    }

    const ushort* qp0 = qb + r0 * 32;
    ushort* ap0 = act + r0 * 32;
#pragma unroll
    for (int grp = 0; grp < 4; ++grp) {   // output cols e in [grp*8, grp*8+8)
        short8_t q0 = *reinterpret_cast<const short8_t*>(qp0 + grp * 8);
        short8_t q1 = *reinterpret_cast<const short8_t*>(qp0 + 32 + grp * 8);
        short8_t o0, o1;
#pragma unroll
        for (int ee = 0; ee < 8; ++ee) {
            const int e = grp * 8 + ee;
            const float4* wre = reinterpret_cast<const float4*>(wr_lds + e * 32);
            float d0 = 0.f, d1 = 0.f;
#pragma unroll
            for (int dq = 0; dq < 8; ++dq) {
                float4 w = wre[dq];
                d0 = fmaf(kvi0[dq * 4 + 0], w.x, d0);
                d1 = fmaf(kvi1[dq * 4 + 0], w.x, d1);
                d0 = fmaf(kvi0[dq * 4 + 1], w.y, d0);
                d1 = fmaf(kvi1[dq * 4 + 1], w.y, d1);
                d0 = fmaf(kvi0[dq * 4 + 2], w.z, d0);
                d1 = fmaf(kvi1[dq * 4 + 2], w.z, d1);
                d0 = fmaf(kvi0[dq * 4 + 3], w.w, d0);
                d1 = fmaf(kvi1[dq * 4 + 3], w.w, d1);
            }
            o0[ee] = f2bs(fmaxf(d0 + us2f((ushort)q0[ee]), 0.f));
            o1[ee] = f2bs(fmaxf(d1 + us2f((ushort)q1[ee]), 0.f));
        }
        *reinterpret_cast<short8_t*>(ap0 + grp * 8) = o0;
        *reinterpret_cast<short8_t*>(ap0 + 32 + grp * 8) = o1;
    }
}

// ---------------- LayerNorm: one wave per row, tmp now BF16 (halved traffic), out row n+1 ----
__global__ __launch_bounds__(256) void ln_kernel(const ushort* __restrict__ tmp,
                                                 const float* __restrict__ b_o,
                                                 const float* __restrict__ gamma,
                                                 const float* __restrict__ beta_ln,
                                                 float* __restrict__ out) {
    const int wave = threadIdx.x >> 6, lane = threadIdx.x & 63;
    const long row = (long)blockIdx.x * 4 + wave;
    const float4 bo = reinterpret_cast<const float4*>(b_o)[lane];
    const float4 g = reinterpret_cast<const float4*>(gamma)[lane];
    const float4 bl = reinterpret_cast<const float4*>(beta_ln)[lane];
    const ushort4 xr = reinterpret_cast<const ushort4*>(tmp + row * HID)[lane];
    float4 x = {us2f(xr.x) + bo.x, us2f(xr.y) + bo.y, us2f(xr.z) + bo.z, us2f(xr.w) + bo.w};
    float s = x.x + x.y + x.z + x.w;
#pragma unroll
    for (int m = 32; m >= 1; m >>= 1) s += __shfl_xor(s, m);
    const float mu = s * (1.f / HID);
    float4 dx = {x.x - mu, x.y - mu, x.z - mu, x.w - mu};
    float sq = dx.x * dx.x + dx.y * dx.y + dx.z * dx.z + dx.w * dx.w;
#pragma unroll
    for (int m = 32; m >= 1; m >>= 1) sq += __shfl_xor(sq, m);
    const float r = rsqrtf(sq * (1.f / HID) + LN_EPS);
    float4 o;
    o.x = dx.x * r * g.x + bl.x;
    o.y = dx.y * r * g.y + bl.y;
    o.z = dx.z * r * g.z + bl.z;
    o.w = dx.w * r * g.w + bl.w;
    reinterpret_cast<float4*>(out + (row + 1) * HID)[lane] = o;
}

extern "C" void kernel_launch(void* const* d_in, const int* in_sizes, int n_in,
                              void* d_out, int out_size, void* d_ws, size_t ws_size,
                              hipStream_t stream) {
    const float* msg    = (const float*)d_in[0];
    const float* Wq     = (const float*)d_in[1];
    const float* Wk     = (const float*)d_in[2];
    const float* Wv     = (const float*)d_in[3];
    const float* Wr     = (const float*)d_in[4];
    const float* walpha = (const float*)d_in[5];
    const float* wbeta  = (const float*)d_in[6];
    const float* Wo     = (const float*)d_in[7];
    const float* bo     = (const float*)d_in[8];
    const float* gamma  = (const float*)d_in[9];
    const float* betaln = (const float*)d_in[10];
    const int*   seg    = (const int*)d_in[11];

    // workspace layout (R1-identical): msgb | qb | kb | vb | wqb wkb wvb wob | gq gk
    // act (bf16) reuses msgb; tmp (now bf16) reuses qb (dead after act).
    char* ws = (char*)d_ws;
    const size_t nh = (size_t)N_BONDS * HID;
    size_t off = 0;
    bf16* msgb = (bf16*)(ws + off); off += nh * 2;
    bf16* qb   = (bf16*)(ws + off); off += nh * 2;
    bf16* kb   = (bf16*)(ws + off); off += nh * 2;
    bf16* vb   = (bf16*)(ws + off); off += nh * 2;
    bf16* wqb  = (bf16*)(ws + off); off += (size_t)HID * HID * 2;
    bf16* wkb  = (bf16*)(ws + off); off += (size_t)HID * HID * 2;
    bf16* wvb  = (bf16*)(ws + off); off += (size_t)HID * HID * 2;
    bf16* wob  = (bf16*)(ws + off); off += (size_t)HID * HID * 2;
    float* gq  = (float*)(ws + off); off += (size_t)NSEG * HID * 4;
    float* gk  = (float*)(ws + off); off += (size_t)NSEG * HID * 4;
    bf16*  act = msgb;
    bf16*  tmp = qb;

    hipMemsetAsync(gq, 0, (size_t)2 * NSEG * HID * 4, stream);
    hipMemsetAsync(d_out, 0, HID * sizeof(float), stream);

    cast_kernel<<<4096, 256, 0, stream>>>(msg, (ushort*)msgb, (int)(nh / 4));
    cast_kernel<<<64, 256, 0, stream>>>(Wq, (ushort*)wqb, HID * HID / 4);
    cast_kernel<<<64, 256, 0, stream>>>(Wk, (ushort*)wkb, HID * HID / 4);
    cast_kernel<<<64, 256, 0, stream>>>(Wv, (ushort*)wvb, HID * HID / 4);
    cast_kernel<<<64, 256, 0, stream>>>(Wo, (ushort*)wob, HID * HID / 4);

    dim3 gg(N_BONDS / 128, 2);
    gemm_bt<bf16><<<gg, 256, 0, stream>>>((const ushort*)msgb, (const ushort*)wqb, qb);
    gemm_bt<bf16><<<gg, 256, 0, stream>>>((const ushort*)msgb, (const ushort*)wkb, kb);
    gemm_bt<bf16><<<gg, 256, 0, stream>>>((const ushort*)msgb, (const ushort*)wvb, vb);

    alpha_gq_kernel<<<N_BONDS / CHUNK, 256, 0, stream>>>(qb, walpha, seg, gq);
    beta_gk_kernel<<<N_BONDS / CHUNK, 256, 0, stream>>>(kb, gq, wbeta, seg, gk);

    act_exact_kernel<<<N_BONDS * 8 / 512, 256, 0, stream>>>((const ushort*)vb, (const ushort*)qb,
                                                            gk, Wr, seg, (ushort*)act);

    gemm_bt<bf16><<<gg, 256, 0, stream>>>((const ushort*)act, (const ushort*)wob, tmp);
    ln_kernel<<<N_BONDS / 4, 256, 0, stream>>>((const ushort*)tmp, bo, gamma, betaln, (float*)d_out);
}